// Round 3
// baseline (2169.372 us; speedup 1.0000x reference)
//
#include <hip/hip_runtime.h>
#include <hip/hip_cooperative_groups.h>
#include <math.h>

namespace cg = cooperative_groups;

#define NN 4096
#define DD 512
#define NSL 16
#define NBATCH 16
#define SCALE_F 0.044194173824159216f
#define LN_EPS_F 1e-5f
#define ATTN_EPS_F 1e-8f

typedef float4 f4;

__device__ __forceinline__ float dot4f(f4 a, f4 b){
    return a.x*b.x + a.y*b.y + a.z*b.z + a.w*b.w;
}

struct Params {
    const float *kin, *vin, *mu, *prompts;
    const float *Wq, *bq, *Wih, *bih, *Whh, *bhh, *W1, *b1, *W2, *b2;
    const float *gk, *bk, *gv, *bv, *gs, *bs, *gff, *bff;
    float *slots, *slots2, *sbuf, *qg, *upd, *hid, *gp, *w;
    float *vmu, *vrstd, *C1p, *C2p, *S, *Mm, *Uwp;
    float *out_slots, *out_attn, *pf, *sf, *sf2;
};

// Phase bodies. Each phase is safe to run as its own kernel launch (no
// cross-block dependencies inside a phase); grid-wide barriers sit between
// phases (grid.sync in coop path, kernel boundary in fallback path).
__device__ void run_phase(const Params& p, int phase, int it){
    __shared__ __align__(16) float smem[8448];   // 33 KB, reused per phase
    const int bx = blockIdx.x, t = threadIdx.x;
    const int lane = t & 63, wv = t >> 6;

    switch (phase){

    case 0: { // broadcast slots_mu -> slots ; v row stats
        int idx = bx*256 + t;                     // 65536
        if (idx < 32768)
            ((f4*)p.slots)[idx] = ((const f4*)p.mu)[idx & 2047];
        const f4* r4 = (const f4*)(p.vin + (size_t)idx*DD);
        float s = 0.f, ss = 0.f;
        for (int c = 0; c < 128; c++){
            f4 x = r4[c];
            s  += x.x+x.y+x.z+x.w;
            ss += x.x*x.x+x.y*x.y+x.z*x.z+x.w*x.w;
        }
        float m = s*(1.f/DD);
        p.vmu[idx] = m;
        p.vrstd[idx] = rsqrtf(ss*(1.f/DD) - m*m + LN_EPS_F);
    } break;

    case 1: { // LN(slots; gs,bs) -> sbuf   (row = bx)
        f4 v = {0.f,0.f,0.f,0.f};
        float s = 0.f, ss = 0.f;
        if (t < 128){
            v = ((const f4*)(p.slots + (size_t)bx*DD))[t];
            s = v.x+v.y+v.z+v.w;
            ss = v.x*v.x+v.y*v.y+v.z*v.z+v.w*v.w;
        }
        for (int o = 32; o; o >>= 1){ s += __shfl_down(s,o); ss += __shfl_down(ss,o); }
        if (lane == 0){ smem[wv] = s; smem[4+wv] = ss; }
        __syncthreads();
        float S = smem[0]+smem[1], SS = smem[4]+smem[5];
        float mu = S*(1.f/DD);
        float rstd = rsqrtf(SS*(1.f/DD) - mu*mu + LN_EPS_F);
        if (t < 128){
            f4 gg = ((const f4*)p.gs)[t], cc4 = ((const f4*)p.bs)[t], o4;
            o4.x = (v.x-mu)*rstd*gg.x + cc4.x;
            o4.y = (v.y-mu)*rstd*gg.y + cc4.y;
            o4.z = (v.z-mu)*rstd*gg.z + cc4.z;
            o4.w = (v.w-mu)*rstd*gg.w + cc4.w;
            ((f4*)(p.sbuf + (size_t)bx*DD))[t] = o4;
        }
    } break;

    case 2: { // q = sbuf@Wq^T + bq ; qg = q*gk ; C1/C2 partials
        int cc = bx & 7, mg = bx >> 3;            // 8 c-chunks x 32 m-groups
        int c = cc*64 + lane;
        int m0 = mg*8 + wv*2;                     // wave -> rows m0, m0+1
        const f4* w4 = (const f4*)(p.Wq + (size_t)c*DD);
        const f4* s4 = (const f4*)p.sbuf;
        float a0 = 0.f, a1 = 0.f;
        for (int k = 0; k < 128; k++){
            f4 wq = w4[k];
            a0 += dot4f(s4[(size_t)m0*128 + k], wq);
            a1 += dot4f(s4[(size_t)(m0+1)*128 + k], wq);
        }
        float bqc = p.bq[c], gkc = p.gk[c], bkc = p.bk[c];
        float q0 = a0 + bqc, q1 = a1 + bqc;
        float qg0 = q0*gkc, qg1 = q1*gkc;
        p.qg[(size_t)m0*DD + c]     = qg0;
        p.qg[(size_t)(m0+1)*DD + c] = qg1;
        float r10 = qg0, r20 = q0*bkc, r11 = qg1, r21 = q1*bkc;
        for (int o = 32; o; o >>= 1){
            r10 += __shfl_down(r10,o); r20 += __shfl_down(r20,o);
            r11 += __shfl_down(r11,o); r21 += __shfl_down(r21,o);
        }
        if (lane == 0){
            p.C1p[cc*256 + m0]   = r10; p.C2p[cc*256 + m0]   = r20;
            p.C1p[cc*256 + m0+1] = r11; p.C2p[cc*256 + m0+1] = r21;
        }
    } break;

    case 3: { // dots + inverted softmax + attn + w   (1 j-row per thread)
        int b = bx & 15, chunk = bx >> 4;
        const f4* qgg = (const f4*)(p.qg + (size_t)b*NSL*DD);
        f4* qs = (f4*)smem;
        for (int idx = t; idx < 2048; idx += 256) qs[idx] = qgg[idx];
        if (t < NSL){
            float c1 = 0.f, c2 = 0.f;
            for (int k = 0; k < 8; k++){
                c1 += p.C1p[k*256 + b*16 + t];
                c2 += p.C2p[k*256 + b*16 + t];
            }
            smem[8192+t] = c1; smem[8208+t] = c2;
        }
        __syncthreads();
        int j = chunk*256 + t;
        const f4* kr = (const f4*)(p.kin + ((size_t)b*NN + j)*DD);
        float acc[NSL];
#pragma unroll
        for (int i = 0; i < NSL; i++) acc[i] = 0.f;
        float s = 0.f, ss = 0.f;
        for (int dd = 0; dd < 128; dd++){
            f4 kv = kr[dd];
            s  += kv.x+kv.y+kv.z+kv.w;
            ss += kv.x*kv.x+kv.y*kv.y+kv.z*kv.z+kv.w*kv.w;
#pragma unroll
            for (int i = 0; i < NSL; i++) acc[i] += dot4f(qs[i*128+dd], kv);
        }
        float mu = s*(1.f/DD);
        float rstd = rsqrtf(ss*(1.f/DD) - mu*mu + LN_EPS_F);
        float d_[NSL], mx = -1e30f;
#pragma unroll
        for (int i = 0; i < NSL; i++){
            d_[i] = SCALE_F*(rstd*(acc[i] - mu*smem[8192+i]) + smem[8208+i]);
            mx = fmaxf(mx, d_[i]);
        }
        float se = 0.f;
#pragma unroll
        for (int i = 0; i < NSL; i++){ d_[i] = __expf(d_[i]-mx); se += d_[i]; }
        float inv = 1.f/se;
        float rv = p.vrstd[(size_t)b*NN + j];
#pragma unroll
        for (int i = 0; i < NSL; i++){
            float a = d_[i]*inv + ATTN_EPS_F;
            p.out_attn[((size_t)b*NSL + i)*NN + j] = a;
            p.w[((size_t)b*NSL + i)*NN + j] = a*rv;
        }
    } break;

    case 4: { // reduceSM then phase-2 partial GEMM (independent sub-steps)
        {   // S[b,i] = sum_j attn ; M[b,i] = sum_j w*mu_v
            int b = bx >> 4, i = bx & 15;
            const float* ar = p.out_attn + ((size_t)b*NSL + i)*NN;
            const float* wr = p.w + ((size_t)b*NSL + i)*NN;
            const float* mr = p.vmu + (size_t)b*NN;
            float s = 0.f, m = 0.f;
            for (int j = t; j < NN; j += 256){ s += ar[j]; m += wr[j]*mr[j]; }
            smem[t] = s; smem[256+t] = m;
            __syncthreads();
            for (int o = 128; o; o >>= 1){
                if (t < o){ smem[t] += smem[t+o]; smem[256+t] += smem[256+t+o]; }
                __syncthreads();
            }
            if (t == 0){ p.S[b*NSL+i] = smem[0]; p.Mm[b*NSL+i] = smem[256]; }
            __syncthreads();
        }
        {   // Uw partials = w-chunk @ v-chunk
            int b = bx & 15, chunk = bx >> 4, jc = chunk*256;
            for (int idx = t; idx < NSL*256; idx += 256){
                int i = idx >> 8, jj = idx & 255;
                smem[jj*20 + i] = p.w[((size_t)b*NSL + i)*NN + jc + jj];
            }
            __syncthreads();
            f4 ax[4], ay[4];
#pragma unroll
            for (int g2 = 0; g2 < 4; g2++){ ax[g2] = f4{0,0,0,0}; ay[g2] = f4{0,0,0,0}; }
            const float2* v2 = (const float2*)(p.vin + ((size_t)b*NN + jc)*DD);
            const f4* wl4 = (const f4*)smem;
            for (int jj = 0; jj < 256; jj++){
                float2 vv = v2[(size_t)jj*256 + t];
#pragma unroll
                for (int g2 = 0; g2 < 4; g2++){
                    f4 wq = wl4[jj*5 + g2];
                    ax[g2].x += wq.x*vv.x; ax[g2].y += wq.y*vv.x; ax[g2].z += wq.z*vv.x; ax[g2].w += wq.w*vv.x;
                    ay[g2].x += wq.x*vv.y; ay[g2].y += wq.y*vv.y; ay[g2].z += wq.z*vv.y; ay[g2].w += wq.w*vv.y;
                }
            }
            float* dst = p.Uwp + (((size_t)chunk*NBATCH + b)*NSL)*DD;
#pragma unroll
            for (int g2 = 0; g2 < 4; g2++){
                const float* px = (const float*)&ax[g2];
                const float* py = (const float*)&ay[g2];
#pragma unroll
                for (int c = 0; c < 4; c++){
                    int i = g2*4 + c;
                    float2 o2; o2.x = px[c]; o2.y = py[c];
                    *(float2*)(dst + (size_t)i*DD + 2*t) = o2;
                }
            }
        }
    } break;

    case 5: { // updates = gv*(sum Uwp - M)/S + bv   (row = bx)
        int m = bx;
        float Sm = p.S[m], Mv = p.Mm[m];
        float rS = 1.f/Sm;
        for (int d = t; d < DD; d += 256){
            float s = 0.f;
            for (int ch = 0; ch < 16; ch++)
                s += p.Uwp[(((size_t)ch*NBATCH + (m>>4))*NSL + (m&15))*DD + d];
            p.upd[(size_t)m*DD + d] = p.gv[d]*(s - Mv)*rS + p.bv[d];
        }
    } break;

    case 6: { // GRU gate matmuls
        int cc = bx & 31, mg = bx >> 5;           // 32 c-chunks x 8 m-groups
        int c = cc*64 + lane;                     // 0..2047
        int m0 = mg*32 + wv*8;                    // wave -> 8 m rows
        int type = c >> 9;
        const f4* x4 = (const f4*)p.upd;
        const f4* h4 = (const f4*)p.slots;
        float acc[8] = {0,0,0,0,0,0,0,0};
        float bias;
        if (type <= 1){
            const f4* wi = (const f4*)(p.Wih + (size_t)c*DD);
            const f4* wh = (const f4*)(p.Whh + (size_t)c*DD);
            for (int k = 0; k < 128; k++){
                f4 a = wi[k], b4 = wh[k];
#pragma unroll
                for (int mm = 0; mm < 8; mm++)
                    acc[mm] += dot4f(a, x4[(size_t)(m0+mm)*128+k]) + dot4f(b4, h4[(size_t)(m0+mm)*128+k]);
            }
            bias = p.bih[c] + p.bhh[c];
        } else if (type == 2){
            const f4* wi = (const f4*)(p.Wih + (size_t)c*DD);
            for (int k = 0; k < 128; k++){
                f4 a = wi[k];
#pragma unroll
                for (int mm = 0; mm < 8; mm++)
                    acc[mm] += dot4f(a, x4[(size_t)(m0+mm)*128+k]);
            }
            bias = p.bih[c];
        } else {
            int cr = c - 512;
            const f4* wh = (const f4*)(p.Whh + (size_t)cr*DD);
            for (int k = 0; k < 128; k++){
                f4 a = wh[k];
#pragma unroll
                for (int mm = 0; mm < 8; mm++)
                    acc[mm] += dot4f(a, h4[(size_t)(m0+mm)*128+k]);
            }
            bias = p.bhh[cr];
        }
#pragma unroll
        for (int mm = 0; mm < 8; mm++)
            p.gp[(size_t)(m0+mm)*2048 + c] = acc[mm] + bias;
    } break;

    case 7: { // GRU elementwise + LN(gff,bff) fused   (row = bx)
        int m = bx;
        const float* g = p.gp + (size_t)m*2048;
        float2 rp = *(const float2*)(g + 2*t);
        float2 zp = *(const float2*)(g + 512 + 2*t);
        float2 nx = *(const float2*)(g + 1024 + 2*t);
        float2 nh = *(const float2*)(g + 1536 + 2*t);
        float2 h  = *(const float2*)(p.slots + (size_t)m*DD + 2*t);
        float2 s2;
        {
            float r = 1.f/(1.f + __expf(-rp.x));
            float z = 1.f/(1.f + __expf(-zp.x));
            float n = tanhf(nx.x + r*nh.x);
            s2.x = (1.f - z)*n + z*h.x;
            r = 1.f/(1.f + __expf(-rp.y));
            z = 1.f/(1.f + __expf(-zp.y));
            n = tanhf(nx.y + r*nh.y);
            s2.y = (1.f - z)*n + z*h.y;
        }
        *(float2*)(p.slots2 + (size_t)m*DD + 2*t) = s2;
        float s = s2.x + s2.y;
        float ss = s2.x*s2.x + s2.y*s2.y;
        for (int o = 32; o; o >>= 1){ s += __shfl_down(s,o); ss += __shfl_down(ss,o); }
        if (lane == 0){ smem[wv] = s; smem[4+wv] = ss; }
        __syncthreads();
        float S = smem[0]+smem[1]+smem[2]+smem[3];
        float SS = smem[4]+smem[5]+smem[6]+smem[7];
        float mu = S*(1.f/DD);
        float rstd = rsqrtf(SS*(1.f/DD) - mu*mu + LN_EPS_F);
        float2 gg = *(const float2*)(p.gff + 2*t);
        float2 bb = *(const float2*)(p.bff + 2*t);
        float2 o2;
        o2.x = (s2.x-mu)*rstd*gg.x + bb.x;
        o2.y = (s2.y-mu)*rstd*gg.y + bb.y;
        *(float2*)(p.sbuf + (size_t)m*DD + 2*t) = o2;
    } break;

    case 8: { // FFN1: hid = relu(sbuf@W1^T + b1)
        int cc = bx & 7, mg = bx >> 3;
        int c = cc*64 + lane;
        int m0 = mg*8 + wv*2;
        const f4* w4 = (const f4*)(p.W1 + (size_t)c*DD);
        const f4* a4 = (const f4*)p.sbuf;
        float a0 = 0.f, a1 = 0.f;
        for (int k = 0; k < 128; k++){
            f4 wq = w4[k];
            a0 += dot4f(a4[(size_t)m0*128+k], wq);
            a1 += dot4f(a4[(size_t)(m0+1)*128+k], wq);
        }
        float bc = p.b1[c];
        p.hid[(size_t)m0*DD + c]     = fmaxf(a0 + bc, 0.f);
        p.hid[(size_t)(m0+1)*DD + c] = fmaxf(a1 + bc, 0.f);
    } break;

    case 9: { // FFN2: slots = slots2 + hid@W2^T + b2  (+out on last iter)
        int cc = bx & 7, mg = bx >> 3;
        int d = cc*64 + lane;
        int m0 = mg*8 + wv*2;
        const f4* w4 = (const f4*)(p.W2 + (size_t)d*DD);
        const f4* h4 = (const f4*)p.hid;
        float a0 = 0.f, a1 = 0.f;
        for (int k = 0; k < 128; k++){
            f4 wq = w4[k];
            a0 += dot4f(h4[(size_t)m0*128+k], wq);
            a1 += dot4f(h4[(size_t)(m0+1)*128+k], wq);
        }
        float bc = p.b2[d];
        float v0 = p.slots2[(size_t)m0*DD + d] + a0 + bc;
        float v1 = p.slots2[(size_t)(m0+1)*DD + d] + a1 + bc;
        p.slots[(size_t)m0*DD + d] = v0;
        p.slots[(size_t)(m0+1)*DD + d] = v1;
        if (it == 2){
            p.out_slots[(size_t)m0*DD + d] = v0;
            p.out_slots[(size_t)(m0+1)*DD + d] = v1;
        }
    } break;

    case 10: { // features pf/sf/sf2
        const float2* p2 = (const float2*)p.prompts;
        float2 pr[NSL];
#pragma unroll
        for (int i = 0; i < NSL; i++) pr[i] = p2[i*256 + t];
        for (int vb = bx; vb < 2048; vb += 256){
            int b = vb >> 7, pc = (vb & 127)*32;
            for (int idx = t; idx < NSL*32; idx += 256){
                int i = idx >> 5, pp = idx & 31;
                smem[i*33 + pp] = p.out_attn[((size_t)b*NSL + i)*NN + pc + pp];
            }
            float2 sl[NSL];
            const float2* s2 = (const float2*)(p.slots + (size_t)b*NSL*DD);
#pragma unroll
            for (int i = 0; i < NSL; i++) sl[i] = s2[i*256 + t];
            __syncthreads();
            for (int pp = 0; pp < 32; pp++){
                float a0=0.f, a1=0.f, c0=0.f, c1=0.f;
#pragma unroll
                for (int i = 0; i < NSL; i++){
                    float a = smem[i*33 + pp];
                    a0 += a*pr[i].x; a1 += a*pr[i].y;
                    c0 += a*sl[i].x; c1 += a*sl[i].y;
                }
                size_t o = ((size_t)b*NN + pc + pp)*DD + 2*t;
                float2 pv; pv.x=a0; pv.y=a1;
                float2 sv; sv.x=c0; sv.y=c1;
                *(float2*)(p.pf + o)  = pv;
                *(float2*)(p.sf + o)  = sv;
                *(float2*)(p.sf2 + o) = sv;
            }
            __syncthreads();
        }
    } break;
    }
}

__global__ __launch_bounds__(256, 1) void mega_coop(Params p){
    cg::grid_group grid = cg::this_grid();
    run_phase(p, 0, 0); grid.sync();
    for (int it = 0; it < 3; it++){
        for (int ph = 1; ph <= 9; ph++){
            run_phase(p, ph, it);
            grid.sync();
        }
    }
    run_phase(p, 10, 0);
}

__global__ __launch_bounds__(256, 1) void mega_phase(Params p, int phase, int it){
    run_phase(p, phase, it);
}

extern "C" void kernel_launch(void* const* d_in, const int* in_sizes, int n_in,
                              void* d_out, int out_size, void* d_ws, size_t ws_size,
                              hipStream_t stream) {
    Params hp;
    hp.kin     = (const float*)d_in[2];
    hp.vin     = (const float*)d_in[3];
    hp.mu      = (const float*)d_in[4];
    hp.prompts = (const float*)d_in[5];
    hp.Wq  = (const float*)d_in[6];
    hp.bq  = (const float*)d_in[7];
    hp.Wih = (const float*)d_in[8];
    hp.bih = (const float*)d_in[9];
    hp.Whh = (const float*)d_in[10];
    hp.bhh = (const float*)d_in[11];
    hp.W1  = (const float*)d_in[12];
    hp.b1  = (const float*)d_in[13];
    hp.W2  = (const float*)d_in[14];
    hp.b2  = (const float*)d_in[15];
    hp.gk  = (const float*)d_in[16];
    hp.bk  = (const float*)d_in[17];
    hp.gv  = (const float*)d_in[18];
    hp.bv  = (const float*)d_in[19];
    hp.gs  = (const float*)d_in[20];
    hp.bs  = (const float*)d_in[21];
    hp.gff = (const float*)d_in[22];
    hp.bff = (const float*)d_in[23];

    float* ws = (float*)d_ws;
    hp.slots  = ws + 0;
    hp.slots2 = ws + 131072;
    hp.sbuf   = ws + 262144;
    hp.qg     = ws + 393216;
    hp.upd    = ws + 524288;
    hp.hid    = ws + 655360;
    hp.gp     = ws + 786432;
    hp.w      = ws + 1310720;
    hp.vmu    = ws + 2359296;
    hp.vrstd  = ws + 2424832;
    hp.C1p    = ws + 2490368;
    hp.C2p    = ws + 2492416;
    hp.S      = ws + 2494464;
    hp.Mm     = ws + 2494720;
    hp.Uwp    = ws + 2494976;   // + 2,097,152 floats -> 18.4 MB total ws use

    float* out   = (float*)d_out;
    hp.out_slots = out;
    hp.out_attn  = out + 131072;
    hp.pf        = out + 1179648;
    hp.sf        = hp.pf + 33554432;
    hp.sf2       = hp.sf + 33554432;

    void* args[] = { &hp };
    hipError_t err = hipLaunchCooperativeKernel((const void*)mega_coop,
                                                dim3(256), dim3(256), args, 0u, stream);
    if (err != hipSuccess){
        (void)hipGetLastError();   // clear the error, take the fallback path
        mega_phase<<<256, 256, 0, stream>>>(hp, 0, 0);
        for (int it = 0; it < 3; it++)
            for (int ph = 1; ph <= 9; ph++)
                mega_phase<<<256, 256, 0, stream>>>(hp, ph, it);
        mega_phase<<<256, 256, 0, stream>>>(hp, 10, 0);
    }
}